// Round 9
// baseline (846.602 us; speedup 1.0000x reference)
//
#include <hip/hip_runtime.h>
#include <hip/hip_fp16.h>

#define NNODES 60000
#define NEDGES 960000
#define NGRAPH 10000

struct __align__(16) H8 { __half2 h[4]; };
struct __align__(8)  H4 { __half2 h[2]; };

typedef _Float16 f16x8 __attribute__((ext_vector_type(8)));
typedef float f32x4 __attribute__((ext_vector_type(4)));

#define LDA 264   // halves; 528 B row stride

// ---------------- degree / CSR build ----------------

__global__ void count_deg_k(const int* __restrict__ ei, int* __restrict__ deg) {
  int e = blockIdx.x * blockDim.x + threadIdx.x;
  atomicAdd(&deg[ei[NEDGES + e]], 1);
}

__global__ void scan1_k(const int* __restrict__ deg, int* __restrict__ rs,
                        int* __restrict__ bsum, float* __restrict__ dinv) {
  __shared__ int s[256];
  int tid = threadIdx.x;
  int i = blockIdx.x * 256 + tid;
  int v = (i < NNODES) ? deg[i] : 0;
  if (i < NNODES) dinv[i] = rsqrtf((float)v + 1.0f);
  int x = v;
  s[tid] = x; __syncthreads();
  #pragma unroll
  for (int off = 1; off < 256; off <<= 1) {
    int t = (tid >= off) ? s[tid - off] : 0;
    __syncthreads();
    x += t; s[tid] = x; __syncthreads();
  }
  if (i < NNODES) rs[i] = x - v;
  if (tid == 255) bsum[blockIdx.x] = x;
}

__global__ void scan2_k(int* __restrict__ bsum, int nb) {
  __shared__ int s[256];
  int tid = threadIdx.x;
  int v = (tid < nb) ? bsum[tid] : 0;
  int x = v; s[tid] = x; __syncthreads();
  #pragma unroll
  for (int off = 1; off < 256; off <<= 1) {
    int t = (tid >= off) ? s[tid - off] : 0;
    __syncthreads();
    x += t; s[tid] = x; __syncthreads();
  }
  if (tid < nb) bsum[tid] = x - v;
}

__global__ void scan3_k(int* __restrict__ rs, const int* __restrict__ bsum) {
  int i = blockIdx.x * 256 + threadIdx.x;
  if (i < NNODES) rs[i] += bsum[blockIdx.x];
  if (i == 0) rs[NNODES] = NEDGES;
}

__global__ void scatter_k(const int* __restrict__ ei, const int* __restrict__ rs,
                          int* __restrict__ cursor, unsigned short* __restrict__ csr) {
  int e = blockIdx.x * blockDim.x + threadIdx.x;
  int s = ei[e], d = ei[NEDGES + e];
  int pos = rs[d] + atomicAdd(&cursor[d], 1);
  csr[pos] = (unsigned short)s;
}

// ---------------- weight transpose+convert ----------------

__global__ void wconv3_k(const float* __restrict__ W1, const float* __restrict__ W2,
                         const float* __restrict__ W3, __half* __restrict__ T1,
                         __half* __restrict__ T2, __half* __restrict__ T3) {
  int n = blockIdx.x & 255, which = blockIdx.x >> 8, k = threadIdx.x;
  const float* W = which == 0 ? W1 : (which == 1 ? W2 : W3);
  __half* T = which == 0 ? T1 : (which == 1 ? T2 : T3);
  T[n * 256 + k] = __float2half_rn(W[k * 256 + n]);
}

// lwhT[l][dim][k] = fp16(l1w[(l*256+k)*32+dim]) for l=0..5  (grid 192 blocks)
__global__ void wconvL_k(const float* __restrict__ l1w, __half* __restrict__ lwhT) {
  int dimg = blockIdx.x;                 // l*32+dim
  int l = dimg >> 5, dim = dimg & 31, k = threadIdx.x;
  lwhT[(size_t)dimg * 256 + k] = __float2half_rn(l1w[((size_t)l * 256 + k) * 32 + dim]);
}

// ---------------- shared GEMM body (A in LDS) ----------------
// main: Y[r] = fp16((A @ W)[r]*dinv[r]), 64x256, waves 2x2 (32 rows x 128 cols).
// proj (interleaved): part[r][0..31] = A @ lwT.
// epilogue: results staged back into As -> fully coalesced H8 stores.

__device__ __forceinline__ void gemm_body(
    _Float16 (*As)[LDA], int m0, int tid,
    const __half* __restrict__ WhT, const __half* __restrict__ lwhT,
    const float* __restrict__ dinv, __half* __restrict__ Y,
    float* __restrict__ part) {
  const int lane = tid & 63;
  const int wid = tid >> 6;
  const int wr = wid >> 1, wc = wid & 1;
  const int li = lane & 15, lg = lane >> 4;

  f32x4 acc[2][8];
  #pragma unroll
  for (int i = 0; i < 2; ++i)
    #pragma unroll
    for (int j = 0; j < 8; ++j) acc[i][j] = (f32x4){0.f, 0.f, 0.f, 0.f};
  f32x4 p0 = (f32x4){0.f, 0.f, 0.f, 0.f};
  f32x4 p1 = (f32x4){0.f, 0.f, 0.f, 0.f};

  #pragma unroll
  for (int k0 = 0; k0 < 256; k0 += 32) {
    f16x8 a0 = *reinterpret_cast<const f16x8*>(&As[wr * 32 + li][k0 + lg * 8]);
    f16x8 a1 = *reinterpret_cast<const f16x8*>(&As[wr * 32 + 16 + li][k0 + lg * 8]);
    f16x8 ap = *reinterpret_cast<const f16x8*>(&As[wid * 16 + li][k0 + lg * 8]);
    f16x8 b[8];
    #pragma unroll
    for (int cf = 0; cf < 8; ++cf)
      b[cf] = *reinterpret_cast<const f16x8*>(
          WhT + (size_t)(wc * 128 + cf * 16 + li) * 256 + k0 + lg * 8);
    f16x8 bp0 = *reinterpret_cast<const f16x8*>(lwhT + (size_t)li * 256 + k0 + lg * 8);
    f16x8 bp1 = *reinterpret_cast<const f16x8*>(lwhT + (size_t)(16 + li) * 256 + k0 + lg * 8);
    #pragma unroll
    for (int cf = 0; cf < 8; ++cf) {
      acc[0][cf] = __builtin_amdgcn_mfma_f32_16x16x32_f16(b[cf], a0, acc[0][cf], 0, 0, 0);
      acc[1][cf] = __builtin_amdgcn_mfma_f32_16x16x32_f16(b[cf], a1, acc[1][cf], 0, 0, 0);
    }
    p0 = __builtin_amdgcn_mfma_f32_16x16x32_f16(bp0, ap, p0, 0, 0, 0);
    p1 = __builtin_amdgcn_mfma_f32_16x16x32_f16(bp1, ap, p1, 0, 0, 0);
  }

  __syncthreads();   // all waves done reading As; safe to overwrite

  #pragma unroll
  for (int rf = 0; rf < 2; ++rf) {
    int row = wr * 32 + rf * 16 + li;
    int r = m0 + row;
    float dv = (r < NNODES) ? dinv[r] : 0.f;
    #pragma unroll
    for (int cf = 0; cf < 8; ++cf) {
      int col = wc * 128 + cf * 16 + lg * 4;
      H4 o;
      o.h[0].x = __float2half_rn(acc[rf][cf][0] * dv);
      o.h[0].y = __float2half_rn(acc[rf][cf][1] * dv);
      o.h[1].x = __float2half_rn(acc[rf][cf][2] * dv);
      o.h[1].y = __float2half_rn(acc[rf][cf][3] * dv);
      *reinterpret_cast<H4*>(&As[row][col]) = o;
    }
  }

  int pr = m0 + wid * 16 + li;
  if (pr < NNODES) {
    float4 v0, v1;
    v0.x = p0[0]; v0.y = p0[1]; v0.z = p0[2]; v0.w = p0[3];
    v1.x = p1[0]; v1.y = p1[1]; v1.z = p1[2]; v1.w = p1[3];
    *reinterpret_cast<float4*>(part + (size_t)pr * 32 + lg * 4) = v0;
    *reinterpret_cast<float4*>(part + (size_t)pr * 32 + 16 + lg * 4) = v1;
  }

  __syncthreads();

  #pragma unroll
  for (int l = 0; l < 8; ++l) {
    int f = l * 256 + tid;
    int row = f >> 5, c8 = (f & 31) * 8;
    int gr = m0 + row;
    if (gr < NNODES)
      *reinterpret_cast<H8*>(Y + (size_t)gr * 256 + c8) =
          *reinterpret_cast<const H8*>(&As[row][c8]);
  }
}

// ---------------- layer 0: stage fp32 state -> fp16 LDS, gemm W1, proj p5 ----------------

__launch_bounds__(256, 3)
__global__ void gemm0_k(const float* __restrict__ Xf, const __half* __restrict__ WhT,
                        const float* __restrict__ dinv, __half* __restrict__ Y,
                        const __half* __restrict__ lwhT, float* __restrict__ part) {
  __shared__ _Float16 As[64][LDA];
  const int tid = threadIdx.x;
  const int m0 = blockIdx.x * 64;
  #pragma unroll
  for (int l = 0; l < 8; ++l) {
    int f = l * 256 + tid;
    int row = f >> 5, c8 = (f & 31) * 8;
    int gr = m0 + row; if (gr >= NNODES) gr = NNODES - 1;
    const float* src = Xf + (size_t)gr * 256 + c8;
    float4 u = *reinterpret_cast<const float4*>(src);
    float4 v = *reinterpret_cast<const float4*>(src + 4);
    H8 o;
    o.h[0].x = __float2half_rn(u.x); o.h[0].y = __float2half_rn(u.y);
    o.h[1].x = __float2half_rn(u.z); o.h[1].y = __float2half_rn(u.w);
    o.h[2].x = __float2half_rn(v.x); o.h[2].y = __float2half_rn(v.y);
    o.h[3].x = __float2half_rn(v.z); o.h[3].y = __float2half_rn(v.w);
    *reinterpret_cast<H8*>(&As[row][c8]) = o;
  }
  __syncthreads();
  gemm_body(As, m0, tid, WhT, lwhT, dinv, Y, part);
}

// ---------------- fused layers 1..4: gather (prev ys) -> LDS, gemm, proj ----------------
// half-wave h gathers nodes m0+h*8 .. +8 (relu(dinv*(self+sum)+bias) -> fp16 As row).

__device__ inline void addH8(float* acc, const H8& v) {
  #pragma unroll
  for (int q = 0; q < 4; ++q) {
    acc[q * 2 + 0] += __low2float(v.h[q]);
    acc[q * 2 + 1] += __high2float(v.h[q]);
  }
}

__launch_bounds__(256, 3)
__global__ void ggemm_k(const __half* __restrict__ ysin, const int* __restrict__ rs,
                        const unsigned short* __restrict__ csr,
                        const float* __restrict__ dinv, const float* __restrict__ bias,
                        const __half* __restrict__ WhT, const __half* __restrict__ lwhT,
                        __half* __restrict__ Yout, float* __restrict__ part) {
  __shared__ _Float16 As[64][LDA];
  const int tid = threadIdx.x;
  const int m0 = blockIdx.x * 64;
  const int half = tid >> 5;
  const int c8 = (tid & 31) * 8;

  float4 b0 = *reinterpret_cast<const float4*>(bias + c8);
  float4 b1 = *reinterpret_cast<const float4*>(bias + c8 + 4);

  for (int i = 0; i < 8; ++i) {
    int d = m0 + half * 8 + i;
    int dc = (d < NNODES) ? d : NNODES - 1;

    float acc[8];
    H8 self = *reinterpret_cast<const H8*>(ysin + (size_t)dc * 256 + c8);
    #pragma unroll
    for (int q = 0; q < 4; ++q) {
      acc[q * 2 + 0] = __low2float(self.h[q]);
      acc[q * 2 + 1] = __high2float(self.h[q]);
    }

    int e = rs[dc], end = rs[dc + 1];
    for (; e + 3 < end; e += 4) {
      int s0 = csr[e], s1 = csr[e + 1], s2 = csr[e + 2], s3 = csr[e + 3];
      H8 v0 = *reinterpret_cast<const H8*>(ysin + (size_t)s0 * 256 + c8);
      H8 v1 = *reinterpret_cast<const H8*>(ysin + (size_t)s1 * 256 + c8);
      H8 v2 = *reinterpret_cast<const H8*>(ysin + (size_t)s2 * 256 + c8);
      H8 v3 = *reinterpret_cast<const H8*>(ysin + (size_t)s3 * 256 + c8);
      addH8(acc, v0);
      addH8(acc, v1);
      addH8(acc, v2);
      addH8(acc, v3);
    }
    for (; e < end; ++e) {
      int s0 = csr[e];
      H8 v0 = *reinterpret_cast<const H8*>(ysin + (size_t)s0 * 256 + c8);
      addH8(acc, v0);
    }

    float dv = dinv[dc];
    float r0 = fmaxf(acc[0] * dv + b0.x, 0.f);
    float r1 = fmaxf(acc[1] * dv + b0.y, 0.f);
    float r2 = fmaxf(acc[2] * dv + b0.z, 0.f);
    float r3 = fmaxf(acc[3] * dv + b0.w, 0.f);
    float r4 = fmaxf(acc[4] * dv + b1.x, 0.f);
    float r5 = fmaxf(acc[5] * dv + b1.y, 0.f);
    float r6 = fmaxf(acc[6] * dv + b1.z, 0.f);
    float r7 = fmaxf(acc[7] * dv + b1.w, 0.f);
    H8 o;
    o.h[0].x = __float2half_rn(r0); o.h[0].y = __float2half_rn(r1);
    o.h[1].x = __float2half_rn(r2); o.h[1].y = __float2half_rn(r3);
    o.h[2].x = __float2half_rn(r4); o.h[2].y = __float2half_rn(r5);
    o.h[3].x = __float2half_rn(r6); o.h[3].y = __float2half_rn(r7);
    *reinterpret_cast<H8*>(&As[half * 8 + i][c8]) = o;
  }
  __syncthreads();
  gemm_body(As, m0, tid, WhT, lwhT, dinv, Yout, part);
}

// ---------------- gather (layer 5 only, r5 proven shape) ----------------

__global__ void gather_k(const __half* __restrict__ ysh, const int* __restrict__ rs,
                         const unsigned short* __restrict__ csr, const float* __restrict__ dinv,
                         const float* __restrict__ bias, __half* __restrict__ out) {
  int tid = threadIdx.x;
  int lane = tid & 63;
  int wave = (blockIdx.x * blockDim.x + tid) >> 6;
  int d = wave * 2 + (lane >> 5);
  int c8 = (lane & 31) * 8;

  float acc[8];
  H8 self = *reinterpret_cast<const H8*>(ysh + (size_t)d * 256 + c8);
  #pragma unroll
  for (int q = 0; q < 4; ++q) {
    acc[q * 2 + 0] = __low2float(self.h[q]);
    acc[q * 2 + 1] = __high2float(self.h[q]);
  }

  int e = rs[d], end = rs[d + 1];
  for (; e + 3 < end; e += 4) {
    int s0 = csr[e], s1 = csr[e + 1], s2 = csr[e + 2], s3 = csr[e + 3];
    H8 v0 = *reinterpret_cast<const H8*>(ysh + (size_t)s0 * 256 + c8);
    H8 v1 = *reinterpret_cast<const H8*>(ysh + (size_t)s1 * 256 + c8);
    H8 v2 = *reinterpret_cast<const H8*>(ysh + (size_t)s2 * 256 + c8);
    H8 v3 = *reinterpret_cast<const H8*>(ysh + (size_t)s3 * 256 + c8);
    addH8(acc, v0);
    addH8(acc, v1);
    addH8(acc, v2);
    addH8(acc, v3);
  }
  for (; e < end; ++e) {
    int s0 = csr[e];
    H8 v0 = *reinterpret_cast<const H8*>(ysh + (size_t)s0 * 256 + c8);
    addH8(acc, v0);
  }

  float dv = dinv[d];
  float4 b0 = *reinterpret_cast<const float4*>(bias + c8);
  float4 b1 = *reinterpret_cast<const float4*>(bias + c8 + 4);
  float r0 = fmaxf(acc[0] * dv + b0.x, 0.f);
  float r1 = fmaxf(acc[1] * dv + b0.y, 0.f);
  float r2 = fmaxf(acc[2] * dv + b0.z, 0.f);
  float r3 = fmaxf(acc[3] * dv + b0.w, 0.f);
  float r4 = fmaxf(acc[4] * dv + b1.x, 0.f);
  float r5 = fmaxf(acc[5] * dv + b1.y, 0.f);
  float r6 = fmaxf(acc[6] * dv + b1.z, 0.f);
  float r7 = fmaxf(acc[7] * dv + b1.w, 0.f);
  H8 o;
  o.h[0].x = __float2half_rn(r0); o.h[0].y = __float2half_rn(r1);
  o.h[1].x = __float2half_rn(r2); o.h[1].y = __float2half_rn(r3);
  o.h[2].x = __float2half_rn(r4); o.h[2].y = __float2half_rn(r5);
  o.h[3].x = __float2half_rn(r6); o.h[3].y = __float2half_rn(r7);
  *reinterpret_cast<H8*>(out + (size_t)d * 256 + c8) = o;
}

// ---------------- standalone skern (o5 -> p4) ----------------

__launch_bounds__(256)
__global__ void skern_k(const __half* __restrict__ in, const float* __restrict__ lw,
                        float* __restrict__ part) {
  __shared__ float os[32][256];
  int tid = threadIdx.x;
  int n0 = blockIdx.x * 32;
  #pragma unroll
  for (int l = 0; l < 4; ++l) {
    int f = tid + l * 256;
    int row = f >> 5, c8 = (f & 31) * 8;
    H8 v = *reinterpret_cast<const H8*>(in + (size_t)(n0 + row) * 256 + c8);
    float* dst = &os[row][c8];
    dst[0] = __low2float(v.h[0]); dst[1] = __high2float(v.h[0]);
    dst[2] = __low2float(v.h[1]); dst[3] = __high2float(v.h[1]);
    dst[4] = __low2float(v.h[2]); dst[5] = __high2float(v.h[2]);
    dst[6] = __low2float(v.h[3]); dst[7] = __high2float(v.h[3]);
  }
  __syncthreads();
  int dim = tid & 31, rblk = tid >> 5;
  float a0 = 0.f, a1 = 0.f, a2 = 0.f, a3 = 0.f;
  #pragma unroll 8
  for (int k = 0; k < 256; ++k) {
    float w = lw[k * 32 + dim];
    a0 += os[rblk * 4 + 0][k] * w;
    a1 += os[rblk * 4 + 1][k] * w;
    a2 += os[rblk * 4 + 2][k] * w;
    a3 += os[rblk * 4 + 3][k] * w;
  }
  int base = (n0 + rblk * 4) * 32 + dim;
  part[base] = a0;
  part[base + 32] = a1;
  part[base + 64] = a2;
  part[base + 96] = a3;
}

// ---------------- fused MLP + readout ----------------

__launch_bounds__(192)
__global__ void mlpfinal_k(const float* __restrict__ p0, const float* __restrict__ p1,
                           const float* __restrict__ p2, const float* __restrict__ p3,
                           const float* __restrict__ p4, const float* __restrict__ p5,
                           const float* __restrict__ action, const float* __restrict__ l1wlast,
                           const float* __restrict__ l1b, const float* __restrict__ l2w,
                           const float* __restrict__ l2b, const float* __restrict__ l3w,
                           const float* __restrict__ l3b, float* __restrict__ out) {
  __shared__ float w2s[1024];
  __shared__ float h1s[6][33];
  __shared__ float red[3];
  int tid = threadIdx.x;
  for (int i = tid; i < 1024; i += 192) w2s[i] = l2w[i];
  int a = tid >> 5, dim = tid & 31;
  int n = blockIdx.x * 6 + a;
  int idx = n * 32 + dim;
  float h1 = l1b[dim] + action[n] * l1wlast[dim]
           + p0[idx] + p1[idx] + p2[idx] + p3[idx] + p4[idx] + p5[idx];
  h1s[a][dim] = fmaxf(h1, 0.f);
  __syncthreads();
  float acc = l2b[dim];
  #pragma unroll
  for (int k = 0; k < 32; ++k) acc += h1s[a][k] * w2s[k * 32 + dim];
  float v = fmaxf(acc, 0.f) * l3w[dim];
  #pragma unroll
  for (int off = 32; off; off >>= 1) v += __shfl_down(v, off, 64);
  int lane = tid & 63, wave = tid >> 6;
  if (lane == 0) red[wave] = v;
  __syncthreads();
  if (tid == 0) out[blockIdx.x] = red[0] + red[1] + red[2] + l3b[0];
}

// ---------------- host ----------------

extern "C" void kernel_launch(void* const* d_in, const int* in_sizes, int n_in,
                              void* d_out, int out_size, void* d_ws, size_t ws_size,
                              hipStream_t stream) {
  const float* state  = (const float*)d_in[0];
  const int*   ei     = (const int*)d_in[1];
  const float* action = (const float*)d_in[2];
  const float* W1 = (const float*)d_in[3];
  const float* b1 = (const float*)d_in[4];
  const float* W2 = (const float*)d_in[5];
  const float* b2 = (const float*)d_in[6];
  const float* W3 = (const float*)d_in[7];
  const float* b3 = (const float*)d_in[8];
  const float* l1w = (const float*)d_in[13];
  const float* l1b = (const float*)d_in[14];
  const float* l2w = (const float*)d_in[15];
  const float* l2b = (const float*)d_in[16];
  const float* l3w = (const float*)d_in[17];
  const float* l3b = (const float*)d_in[18];
  float* out = (float*)d_out;

  char* base = (char*)d_ws;
  size_t off = 0;
  auto carve = [&](size_t bytes) {
    char* q = base + off;
    off += (bytes + 255) & ~(size_t)255;
    return q;
  };
  __half* ysA    = (__half*)carve((size_t)NNODES * 256 * 2);
  __half* ysB    = (__half*)carve((size_t)NNODES * 256 * 2);
  __half* obufh  = (__half*)carve((size_t)NNODES * 256 * 2);
  __half* whT1   = (__half*)carve(256 * 256 * 2);
  __half* whT2   = (__half*)carve(256 * 256 * 2);
  __half* whT3   = (__half*)carve(256 * 256 * 2);
  __half* lwhT   = (__half*)carve(6 * 32 * 256 * 2);   // [l][dim][k], l=0..5
  float* parts[6];
  for (int i = 0; i < 6; ++i) parts[i] = (float*)carve((size_t)NNODES * 32 * 4);
  float* dinv  = (float*)carve(NNODES * 4);
  char*  zbase = (char*)carve(0);
  int*   deg   = (int*)carve(NNODES * 4);
  int*   cursor= (int*)carve(NNODES * 4);
  size_t zlen  = (size_t)((char*)carve(0) - zbase);
  int*   rs    = (int*)carve((NNODES + 1) * 4);
  unsigned short* csr = (unsigned short*)carve((size_t)NEDGES * 2);
  int*   bsum  = (int*)carve(256 * 4);

  hipMemsetAsync(zbase, 0, zlen, stream);

  wconv3_k<<<256 * 3, 256, 0, stream>>>(W1, W2, W3, whT1, whT2, whT3);
  wconvL_k<<<192, 256, 0, stream>>>(l1w, lwhT);

  count_deg_k<<<NEDGES / 256, 256, 0, stream>>>(ei, deg);
  int nb = (NNODES + 255) / 256;
  scan1_k<<<nb, 256, 0, stream>>>(deg, rs, bsum, dinv);
  scan2_k<<<1, 256, 0, stream>>>(bsum, nb);
  scan3_k<<<nb, 256, 0, stream>>>(rs, bsum);
  scatter_k<<<NEDGES / 256, 256, 0, stream>>>(ei, rs, cursor, csr);

  int mblocks = (NNODES + 63) / 64;   // 938

  // layer 0: state @ W1 -> ysA ; proj slice5 -> p5 (state)
  gemm0_k<<<mblocks, 256, 0, stream>>>(state, whT1, dinv, ysA,
                                       lwhT + (size_t)5 * 32 * 256, parts[5]);
  // fused layers: gather(ys, b) -> o_l in LDS -> gemm W_{l+1} -> ys ; proj o_l
  // fused1: ysA -> o1 (b1) -> @W2 -> ysB ; p0
  ggemm_k<<<mblocks, 256, 0, stream>>>(ysA, rs, csr, dinv, b1, whT2,
                                       lwhT + (size_t)0 * 32 * 256, ysB, parts[0]);
  // fused2: ysB -> o2 (b2) -> @W3 -> ysA ; p1
  ggemm_k<<<mblocks, 256, 0, stream>>>(ysB, rs, csr, dinv, b2, whT3,
                                       lwhT + (size_t)1 * 32 * 256, ysA, parts[1]);
  // fused3: ysA -> o3 (b3) -> @W3 -> ysB ; p2
  ggemm_k<<<mblocks, 256, 0, stream>>>(ysA, rs, csr, dinv, b3, whT3,
                                       lwhT + (size_t)2 * 32 * 256, ysB, parts[2]);
  // fused4: ysB -> o4 (b3) -> @W3 -> ysA ; p3
  ggemm_k<<<mblocks, 256, 0, stream>>>(ysB, rs, csr, dinv, b3, whT3,
                                       lwhT + (size_t)3 * 32 * 256, ysA, parts[3]);
  // layer5: gather ysA (b3) -> o5 ; skern -> p4
  gather_k<<<NNODES / 8, 256, 0, stream>>>(ysA, rs, csr, dinv, b3, obufh);
  skern_k<<<NNODES / 32, 256, 0, stream>>>(obufh, l1w + 1024 * 32, parts[4]);

  mlpfinal_k<<<NGRAPH, 192, 0, stream>>>(parts[0], parts[1], parts[2], parts[3], parts[4],
                                         parts[5], action, l1w + 1536 * 32, l1b, l2w, l2b,
                                         l3w, l3b, out);
}

// Round 10
// 735.501 us; speedup vs baseline: 1.1511x; 1.1511x over previous
//
#include <hip/hip_runtime.h>
#include <hip/hip_fp16.h>

#define NNODES 60000
#define NEDGES 960000
#define NGRAPH 10000

struct __align__(16) H8 { __half2 h[4]; };
struct __align__(8)  H4 { __half2 h[2]; };

typedef _Float16 f16x8 __attribute__((ext_vector_type(8)));
typedef float f32x4 __attribute__((ext_vector_type(4)));

#define LDA 264   // halves; 528 B row stride (16B-aligned rows)

// ---------------- degree / CSR build ----------------

__global__ void count_deg_k(const int* __restrict__ ei, int* __restrict__ deg) {
  int e = blockIdx.x * blockDim.x + threadIdx.x;
  atomicAdd(&deg[ei[NEDGES + e]], 1);
}

__global__ void scan1_k(const int* __restrict__ deg, int* __restrict__ rs,
                        int* __restrict__ bsum, float* __restrict__ dinv) {
  __shared__ int s[256];
  int tid = threadIdx.x;
  int i = blockIdx.x * 256 + tid;
  int v = (i < NNODES) ? deg[i] : 0;
  if (i < NNODES) dinv[i] = rsqrtf((float)v + 1.0f);
  int x = v;
  s[tid] = x; __syncthreads();
  #pragma unroll
  for (int off = 1; off < 256; off <<= 1) {
    int t = (tid >= off) ? s[tid - off] : 0;
    __syncthreads();
    x += t; s[tid] = x; __syncthreads();
  }
  if (i < NNODES) rs[i] = x - v;
  if (tid == 255) bsum[blockIdx.x] = x;
}

__global__ void scan2_k(int* __restrict__ bsum, int nb) {
  __shared__ int s[256];
  int tid = threadIdx.x;
  int v = (tid < nb) ? bsum[tid] : 0;
  int x = v; s[tid] = x; __syncthreads();
  #pragma unroll
  for (int off = 1; off < 256; off <<= 1) {
    int t = (tid >= off) ? s[tid - off] : 0;
    __syncthreads();
    x += t; s[tid] = x; __syncthreads();
  }
  if (tid < nb) bsum[tid] = x - v;
}

__global__ void scan3_k(int* __restrict__ rs, const int* __restrict__ bsum) {
  int i = blockIdx.x * 256 + threadIdx.x;
  if (i < NNODES) rs[i] += bsum[blockIdx.x];
  if (i == 0) rs[NNODES] = NEDGES;
}

__global__ void scatter_k(const int* __restrict__ ei, const int* __restrict__ rs,
                          int* __restrict__ cursor, unsigned short* __restrict__ csr) {
  int e = blockIdx.x * blockDim.x + threadIdx.x;
  int s = ei[e], d = ei[NEDGES + e];
  int pos = rs[d] + atomicAdd(&cursor[d], 1);
  csr[pos] = (unsigned short)s;
}

// ---------------- weight packing into MFMA fragment order ----------------
// Bp chunk c = kq*16 + wc*8 + cf (128 chunks x 1KB). Lane l, elem j holds
// W[k][n] with n=(wc*8+cf)*16+(l&15), k=kq*32+(l>>4)*8+j  ->  load is
// base(c) + lane*16B, perfectly coalesced.

__global__ void wpack_k(const float* __restrict__ W1, const float* __restrict__ W2,
                        const float* __restrict__ W3, __half* __restrict__ B1,
                        __half* __restrict__ B2, __half* __restrict__ B3) {
  int which = blockIdx.x >> 7;
  int c = blockIdx.x & 127;
  const float* W = which == 0 ? W1 : (which == 1 ? W2 : W3);
  __half* Bp = which == 0 ? B1 : (which == 1 ? B2 : B3);
  int kq = c >> 4, wcf = c & 15;
  int t = threadIdx.x;          // 2 halves per thread
  int l = t >> 2;
  int j0 = (t & 3) * 2;
  int li = l & 15, lg = l >> 4;
  int n = wcf * 16 + li;
  int k = kq * 32 + lg * 8 + j0;
  __half2 v;
  v.x = __float2half_rn(W[(size_t)k * 256 + n]);
  v.y = __float2half_rn(W[(size_t)(k + 1) * 256 + n]);
  *reinterpret_cast<__half2*>(Bp + (size_t)c * 512 + 2 * t) = v;
}

// Pp: projection slices of lin1_w. chunk b = l*16 + kq*2 + hh (96 chunks x 1KB).
// lane l', elem j holds l1w[(l*256+k)*32+dim], dim=hh*16+(l'&15), k=kq*32+(l'>>4)*8+j.

__global__ void lwpack_k(const float* __restrict__ l1w, __half* __restrict__ Pp) {
  int b = blockIdx.x;
  int l = b >> 4, cp = b & 15;
  int kq = cp >> 1, hh = cp & 1;
  int t = threadIdx.x;
  int ln = t >> 2;
  int j0 = (t & 3) * 2;
  int li = ln & 15, lg = ln >> 4;
  int dim = hh * 16 + li;
  int k = kq * 32 + lg * 8 + j0;
  __half2 v;
  v.x = __float2half_rn(l1w[((size_t)l * 256 + k) * 32 + dim]);
  v.y = __float2half_rn(l1w[((size_t)l * 256 + k + 1) * 32 + dim]);
  *reinterpret_cast<__half2*>(Pp + (size_t)b * 512 + 2 * t) = v;
}

// ---------------- shared GEMM body (A in LDS, packed B) ----------------

__device__ __forceinline__ void gemm_body(
    _Float16 (*As)[LDA], int m0, int tid,
    const __half* __restrict__ Bp, const __half* __restrict__ Pp,
    const float* __restrict__ dinv, __half* __restrict__ Y,
    float* __restrict__ part) {
  const int lane = tid & 63;
  const int wid = tid >> 6;
  const int wr = wid >> 1, wc = wid & 1;
  const int li = lane & 15, lg = lane >> 4;

  f32x4 acc[2][8];
  #pragma unroll
  for (int i = 0; i < 2; ++i)
    #pragma unroll
    for (int j = 0; j < 8; ++j) acc[i][j] = (f32x4){0.f, 0.f, 0.f, 0.f};
  f32x4 p0 = (f32x4){0.f, 0.f, 0.f, 0.f};
  f32x4 p1 = (f32x4){0.f, 0.f, 0.f, 0.f};

  const __half* bwave = Bp + (size_t)wc * 8 * 512 + lane * 8;
  const __half* pbase = Pp + lane * 8;

  #pragma unroll
  for (int kq = 0; kq < 8; ++kq) {
    int k0 = kq * 32;
    f16x8 a0 = *reinterpret_cast<const f16x8*>(&As[wr * 32 + li][k0 + lg * 8]);
    f16x8 a1 = *reinterpret_cast<const f16x8*>(&As[wr * 32 + 16 + li][k0 + lg * 8]);
    f16x8 ap = *reinterpret_cast<const f16x8*>(&As[wid * 16 + li][k0 + lg * 8]);
    f16x8 b[8];
    #pragma unroll
    for (int cf = 0; cf < 8; ++cf)
      b[cf] = *reinterpret_cast<const f16x8*>(bwave + ((size_t)kq * 16 + cf) * 512);
    f16x8 bp0 = *reinterpret_cast<const f16x8*>(pbase + ((size_t)kq * 2 + 0) * 512);
    f16x8 bp1 = *reinterpret_cast<const f16x8*>(pbase + ((size_t)kq * 2 + 1) * 512);
    #pragma unroll
    for (int cf = 0; cf < 8; ++cf) {
      acc[0][cf] = __builtin_amdgcn_mfma_f32_16x16x32_f16(b[cf], a0, acc[0][cf], 0, 0, 0);
      acc[1][cf] = __builtin_amdgcn_mfma_f32_16x16x32_f16(b[cf], a1, acc[1][cf], 0, 0, 0);
    }
    p0 = __builtin_amdgcn_mfma_f32_16x16x32_f16(bp0, ap, p0, 0, 0, 0);
    p1 = __builtin_amdgcn_mfma_f32_16x16x32_f16(bp1, ap, p1, 0, 0, 0);
  }

  __syncthreads();   // all waves done reading As; safe to overwrite

  #pragma unroll
  for (int rf = 0; rf < 2; ++rf) {
    int row = wr * 32 + rf * 16 + li;
    int r = m0 + row;
    float dv = (r < NNODES) ? dinv[r] : 0.f;
    #pragma unroll
    for (int cf = 0; cf < 8; ++cf) {
      int col = wc * 128 + cf * 16 + lg * 4;
      H4 o;
      o.h[0].x = __float2half_rn(acc[rf][cf][0] * dv);
      o.h[0].y = __float2half_rn(acc[rf][cf][1] * dv);
      o.h[1].x = __float2half_rn(acc[rf][cf][2] * dv);
      o.h[1].y = __float2half_rn(acc[rf][cf][3] * dv);
      *reinterpret_cast<H4*>(&As[row][col]) = o;
    }
  }

  int pr = m0 + wid * 16 + li;
  if (pr < NNODES) {
    float4 v0, v1;
    v0.x = p0[0]; v0.y = p0[1]; v0.z = p0[2]; v0.w = p0[3];
    v1.x = p1[0]; v1.y = p1[1]; v1.z = p1[2]; v1.w = p1[3];
    *reinterpret_cast<float4*>(part + (size_t)pr * 32 + lg * 4) = v0;
    *reinterpret_cast<float4*>(part + (size_t)pr * 32 + 16 + lg * 4) = v1;
  }

  __syncthreads();

  #pragma unroll
  for (int l = 0; l < 8; ++l) {
    int f = l * 256 + tid;
    int row = f >> 5, c8 = (f & 31) * 8;
    int gr = m0 + row;
    if (gr < NNODES)
      *reinterpret_cast<H8*>(Y + (size_t)gr * 256 + c8) =
          *reinterpret_cast<const H8*>(&As[row][c8]);
  }
}

// ---------------- layer 0: fp32 state -> fp16 LDS, gemm W1, proj p5 ----------------

__launch_bounds__(256, 3)
__global__ void gemm0_k(const float* __restrict__ Xf, const __half* __restrict__ Bp,
                        const float* __restrict__ dinv, __half* __restrict__ Y,
                        const __half* __restrict__ Pp, float* __restrict__ part) {
  __shared__ _Float16 As[64][LDA];
  const int tid = threadIdx.x;
  const int m0 = blockIdx.x * 64;
  #pragma unroll
  for (int l = 0; l < 8; ++l) {
    int f = l * 256 + tid;
    int row = f >> 5, c8 = (f & 31) * 8;
    int gr = m0 + row; if (gr >= NNODES) gr = NNODES - 1;
    const float* src = Xf + (size_t)gr * 256 + c8;
    float4 u = *reinterpret_cast<const float4*>(src);
    float4 v = *reinterpret_cast<const float4*>(src + 4);
    H8 o;
    o.h[0].x = __float2half_rn(u.x); o.h[0].y = __float2half_rn(u.y);
    o.h[1].x = __float2half_rn(u.z); o.h[1].y = __float2half_rn(u.w);
    o.h[2].x = __float2half_rn(v.x); o.h[2].y = __float2half_rn(v.y);
    o.h[3].x = __float2half_rn(v.z); o.h[3].y = __float2half_rn(v.w);
    *reinterpret_cast<H8*>(&As[row][c8]) = o;
  }
  __syncthreads();
  gemm_body(As, m0, tid, Bp, Pp, dinv, Y, part);
}

// ---------------- layers 1..4: fp16 activations from global, gemm, proj ----------------

__launch_bounds__(256, 3)
__global__ void gemm_k(const __half* __restrict__ Xh, const __half* __restrict__ Bp,
                       const float* __restrict__ dinv, __half* __restrict__ Y,
                       const __half* __restrict__ Pp, float* __restrict__ part) {
  __shared__ _Float16 As[64][LDA];
  const int tid = threadIdx.x;
  const int m0 = blockIdx.x * 64;
  #pragma unroll
  for (int l = 0; l < 8; ++l) {
    int f = l * 256 + tid;
    int row = f >> 5, c8 = (f & 31) * 8;
    int gr = m0 + row; if (gr >= NNODES) gr = NNODES - 1;
    *reinterpret_cast<H8*>(&As[row][c8]) =
        *reinterpret_cast<const H8*>(Xh + (size_t)gr * 256 + c8);
  }
  __syncthreads();
  gemm_body(As, m0, tid, Bp, Pp, dinv, Y, part);
}

// ---------------- gather (r5 proven shape): half-wave per node ----------------

__device__ inline void addH8(float* acc, const H8& v) {
  #pragma unroll
  for (int q = 0; q < 4; ++q) {
    acc[q * 2 + 0] += __low2float(v.h[q]);
    acc[q * 2 + 1] += __high2float(v.h[q]);
  }
}

__global__ void gather_k(const __half* __restrict__ ysh, const int* __restrict__ rs,
                         const unsigned short* __restrict__ csr, const float* __restrict__ dinv,
                         const float* __restrict__ bias, __half* __restrict__ out) {
  int tid = threadIdx.x;
  int lane = tid & 63;
  int wave = (blockIdx.x * blockDim.x + tid) >> 6;
  int d = wave * 2 + (lane >> 5);
  int c8 = (lane & 31) * 8;

  float acc[8];
  H8 self = *reinterpret_cast<const H8*>(ysh + (size_t)d * 256 + c8);
  #pragma unroll
  for (int q = 0; q < 4; ++q) {
    acc[q * 2 + 0] = __low2float(self.h[q]);
    acc[q * 2 + 1] = __high2float(self.h[q]);
  }

  int e = rs[d], end = rs[d + 1];
  for (; e + 3 < end; e += 4) {
    int s0 = csr[e], s1 = csr[e + 1], s2 = csr[e + 2], s3 = csr[e + 3];
    H8 v0 = *reinterpret_cast<const H8*>(ysh + (size_t)s0 * 256 + c8);
    H8 v1 = *reinterpret_cast<const H8*>(ysh + (size_t)s1 * 256 + c8);
    H8 v2 = *reinterpret_cast<const H8*>(ysh + (size_t)s2 * 256 + c8);
    H8 v3 = *reinterpret_cast<const H8*>(ysh + (size_t)s3 * 256 + c8);
    addH8(acc, v0);
    addH8(acc, v1);
    addH8(acc, v2);
    addH8(acc, v3);
  }
  for (; e < end; ++e) {
    int s0 = csr[e];
    H8 v0 = *reinterpret_cast<const H8*>(ysh + (size_t)s0 * 256 + c8);
    addH8(acc, v0);
  }

  float dv = dinv[d];
  float4 b0 = *reinterpret_cast<const float4*>(bias + c8);
  float4 b1 = *reinterpret_cast<const float4*>(bias + c8 + 4);
  float r0 = fmaxf(acc[0] * dv + b0.x, 0.f);
  float r1 = fmaxf(acc[1] * dv + b0.y, 0.f);
  float r2 = fmaxf(acc[2] * dv + b0.z, 0.f);
  float r3 = fmaxf(acc[3] * dv + b0.w, 0.f);
  float r4 = fmaxf(acc[4] * dv + b1.x, 0.f);
  float r5 = fmaxf(acc[5] * dv + b1.y, 0.f);
  float r6 = fmaxf(acc[6] * dv + b1.z, 0.f);
  float r7 = fmaxf(acc[7] * dv + b1.w, 0.f);
  H8 o;
  o.h[0].x = __float2half_rn(r0); o.h[0].y = __float2half_rn(r1);
  o.h[1].x = __float2half_rn(r2); o.h[1].y = __float2half_rn(r3);
  o.h[2].x = __float2half_rn(r4); o.h[2].y = __float2half_rn(r5);
  o.h[3].x = __float2half_rn(r6); o.h[3].y = __float2half_rn(r7);
  *reinterpret_cast<H8*>(out + (size_t)d * 256 + c8) = o;
}

// ---------------- standalone skern (o5 -> p4) ----------------

__launch_bounds__(256)
__global__ void skern_k(const __half* __restrict__ in, const float* __restrict__ lw,
                        float* __restrict__ part) {
  __shared__ float os[32][256];
  int tid = threadIdx.x;
  int n0 = blockIdx.x * 32;
  #pragma unroll
  for (int l = 0; l < 4; ++l) {
    int f = tid + l * 256;
    int row = f >> 5, c8 = (f & 31) * 8;
    H8 v = *reinterpret_cast<const H8*>(in + (size_t)(n0 + row) * 256 + c8);
    float* dst = &os[row][c8];
    dst[0] = __low2float(v.h[0]); dst[1] = __high2float(v.h[0]);
    dst[2] = __low2float(v.h[1]); dst[3] = __high2float(v.h[1]);
    dst[4] = __low2float(v.h[2]); dst[5] = __high2float(v.h[2]);
    dst[6] = __low2float(v.h[3]); dst[7] = __high2float(v.h[3]);
  }
  __syncthreads();
  int dim = tid & 31, rblk = tid >> 5;
  float a0 = 0.f, a1 = 0.f, a2 = 0.f, a3 = 0.f;
  #pragma unroll 8
  for (int k = 0; k < 256; ++k) {
    float w = lw[k * 32 + dim];
    a0 += os[rblk * 4 + 0][k] * w;
    a1 += os[rblk * 4 + 1][k] * w;
    a2 += os[rblk * 4 + 2][k] * w;
    a3 += os[rblk * 4 + 3][k] * w;
  }
  int base = (n0 + rblk * 4) * 32 + dim;
  part[base] = a0;
  part[base + 32] = a1;
  part[base + 64] = a2;
  part[base + 96] = a3;
}

// ---------------- fused MLP + readout ----------------

__launch_bounds__(192)
__global__ void mlpfinal_k(const float* __restrict__ p0, const float* __restrict__ p1,
                           const float* __restrict__ p2, const float* __restrict__ p3,
                           const float* __restrict__ p4, const float* __restrict__ p5,
                           const float* __restrict__ action, const float* __restrict__ l1wlast,
                           const float* __restrict__ l1b, const float* __restrict__ l2w,
                           const float* __restrict__ l2b, const float* __restrict__ l3w,
                           const float* __restrict__ l3b, float* __restrict__ out) {
  __shared__ float w2s[1024];
  __shared__ float h1s[6][33];
  __shared__ float red[3];
  int tid = threadIdx.x;
  for (int i = tid; i < 1024; i += 192) w2s[i] = l2w[i];
  int a = tid >> 5, dim = tid & 31;
  int n = blockIdx.x * 6 + a;
  int idx = n * 32 + dim;
  float h1 = l1b[dim] + action[n] * l1wlast[dim]
           + p0[idx] + p1[idx] + p2[idx] + p3[idx] + p4[idx] + p5[idx];
  h1s[a][dim] = fmaxf(h1, 0.f);
  __syncthreads();
  float acc = l2b[dim];
  #pragma unroll
  for (int k = 0; k < 32; ++k) acc += h1s[a][k] * w2s[k * 32 + dim];
  float v = fmaxf(acc, 0.f) * l3w[dim];
  #pragma unroll
  for (int off = 32; off; off >>= 1) v += __shfl_down(v, off, 64);
  int lane = tid & 63, wave = tid >> 6;
  if (lane == 0) red[wave] = v;
  __syncthreads();
  if (tid == 0) out[blockIdx.x] = red[0] + red[1] + red[2] + l3b[0];
}

// ---------------- host ----------------

extern "C" void kernel_launch(void* const* d_in, const int* in_sizes, int n_in,
                              void* d_out, int out_size, void* d_ws, size_t ws_size,
                              hipStream_t stream) {
  const float* state  = (const float*)d_in[0];
  const int*   ei     = (const int*)d_in[1];
  const float* action = (const float*)d_in[2];
  const float* W1 = (const float*)d_in[3];
  const float* b1 = (const float*)d_in[4];
  const float* W2 = (const float*)d_in[5];
  const float* b2 = (const float*)d_in[6];
  const float* W3 = (const float*)d_in[7];
  const float* b3 = (const float*)d_in[8];
  const float* l1w = (const float*)d_in[13];
  const float* l1b = (const float*)d_in[14];
  const float* l2w = (const float*)d_in[15];
  const float* l2b = (const float*)d_in[16];
  const float* l3w = (const float*)d_in[17];
  const float* l3b = (const float*)d_in[18];
  float* out = (float*)d_out;

  char* base = (char*)d_ws;
  size_t off = 0;
  auto carve = [&](size_t bytes) {
    char* q = base + off;
    off += (bytes + 255) & ~(size_t)255;
    return q;
  };
  __half* ysh   = (__half*)carve((size_t)NNODES * 256 * 2);
  __half* obufh = (__half*)carve((size_t)NNODES * 256 * 2);
  __half* Bp1   = (__half*)carve(128 * 512 * 2);
  __half* Bp2   = (__half*)carve(128 * 512 * 2);
  __half* Bp3   = (__half*)carve(128 * 512 * 2);
  __half* Pp    = (__half*)carve(96 * 512 * 2);   // 6 slices x 16 chunks
  float* parts[6];
  for (int i = 0; i < 6; ++i) parts[i] = (float*)carve((size_t)NNODES * 32 * 4);
  float* dinv  = (float*)carve(NNODES * 4);
  char*  zbase = (char*)carve(0);
  int*   deg   = (int*)carve(NNODES * 4);
  int*   cursor= (int*)carve(NNODES * 4);
  size_t zlen  = (size_t)((char*)carve(0) - zbase);
  int*   rs    = (int*)carve((NNODES + 1) * 4);
  unsigned short* csr = (unsigned short*)carve((size_t)NEDGES * 2);
  int*   bsum  = (int*)carve(256 * 4);

  hipMemsetAsync(zbase, 0, zlen, stream);

  wpack_k<<<128 * 3, 256, 0, stream>>>(W1, W2, W3, Bp1, Bp2, Bp3);
  lwpack_k<<<96, 256, 0, stream>>>(l1w, Pp);

  count_deg_k<<<NEDGES / 256, 256, 0, stream>>>(ei, deg);
  int nb = (NNODES + 255) / 256;
  scan1_k<<<nb, 256, 0, stream>>>(deg, rs, bsum, dinv);
  scan2_k<<<1, 256, 0, stream>>>(bsum, nb);
  scan3_k<<<nb, 256, 0, stream>>>(rs, bsum);
  scatter_k<<<NEDGES / 256, 256, 0, stream>>>(ei, rs, cursor, csr);

  int mblocks = (NNODES + 63) / 64;   // 938
  const __half* Bps[5] = {Bp1, Bp2, Bp3, Bp3, Bp3};
  const float*  bs[5]  = {b1, b2, b3, b3, b3};

  // layer 0: state @ W1 -> ysh ; proj p5 (state @ lw5)
  gemm0_k<<<mblocks, 256, 0, stream>>>(state, Bp1, dinv, ysh,
                                       Pp + (size_t)5 * 16 * 512, parts[5]);
  for (int layer = 1; layer < 5; ++layer) {
    // gather ys -> o_layer (obufh)
    gather_k<<<NNODES / 8, 256, 0, stream>>>(ysh, rs, csr, dinv, bs[layer - 1], obufh);
    // gemm o_layer @ W_{layer+1} -> ysh ; proj p_{layer-1} = o_layer @ lw_{layer-1}
    gemm_k<<<mblocks, 256, 0, stream>>>(obufh, Bps[layer], dinv, ysh,
                                        Pp + (size_t)(layer - 1) * 16 * 512, parts[layer - 1]);
  }
  // layer 5: gather -> o5 ; skern -> p4
  gather_k<<<NNODES / 8, 256, 0, stream>>>(ysh, rs, csr, dinv, b3, obufh);
  skern_k<<<NNODES / 32, 256, 0, stream>>>(obufh, l1w + 1024 * 32, parts[4]);

  mlpfinal_k<<<NGRAPH, 192, 0, stream>>>(parts[0], parts[1], parts[2], parts[3], parts[4],
                                         parts[5], action, l1w + 1536 * 32, l1b, l2w, l2b,
                                         l3w, l3b, out);
}

// Round 11
// 646.640 us; speedup vs baseline: 1.3092x; 1.1374x over previous
//
#include <hip/hip_runtime.h>
#include <hip/hip_fp16.h>

#define NNODES 60000
#define NEDGES 960000
#define NGRAPH 10000

struct __align__(16) H8 { __half2 h[4]; };
struct __align__(8)  H4 { __half2 h[2]; };

typedef _Float16 f16x8 __attribute__((ext_vector_type(8)));
typedef float f32x4 __attribute__((ext_vector_type(4)));

#define LDA 264   // halves; 528 B row stride (16B-aligned rows)

// ---------------- degree / CSR build ----------------

__global__ void count_deg_k(const int* __restrict__ ei, int* __restrict__ deg) {
  int e = blockIdx.x * blockDim.x + threadIdx.x;
  atomicAdd(&deg[ei[NEDGES + e]], 1);
}

__global__ void scan1_k(const int* __restrict__ deg, int* __restrict__ rs,
                        int* __restrict__ bsum, float* __restrict__ dinv) {
  __shared__ int s[256];
  int tid = threadIdx.x;
  int i = blockIdx.x * 256 + tid;
  int v = (i < NNODES) ? deg[i] : 0;
  if (i < NNODES) dinv[i] = rsqrtf((float)v + 1.0f);
  int x = v;
  s[tid] = x; __syncthreads();
  #pragma unroll
  for (int off = 1; off < 256; off <<= 1) {
    int t = (tid >= off) ? s[tid - off] : 0;
    __syncthreads();
    x += t; s[tid] = x; __syncthreads();
  }
  if (i < NNODES) rs[i] = x - v;
  if (tid == 255) bsum[blockIdx.x] = x;
}

__global__ void scan2_k(int* __restrict__ bsum, int nb) {
  __shared__ int s[256];
  int tid = threadIdx.x;
  int v = (tid < nb) ? bsum[tid] : 0;
  int x = v; s[tid] = x; __syncthreads();
  #pragma unroll
  for (int off = 1; off < 256; off <<= 1) {
    int t = (tid >= off) ? s[tid - off] : 0;
    __syncthreads();
    x += t; s[tid] = x; __syncthreads();
  }
  if (tid < nb) bsum[tid] = x - v;
}

__global__ void scan3_k(int* __restrict__ rs, const int* __restrict__ bsum) {
  int i = blockIdx.x * 256 + threadIdx.x;
  if (i < NNODES) rs[i] += bsum[blockIdx.x];
  if (i == 0) rs[NNODES] = NEDGES;
}

__global__ void scatter_k(const int* __restrict__ ei, const int* __restrict__ rs,
                          int* __restrict__ cursor, unsigned short* __restrict__ csr) {
  int e = blockIdx.x * blockDim.x + threadIdx.x;
  int s = ei[e], d = ei[NEDGES + e];
  int pos = rs[d] + atomicAdd(&cursor[d], 1);
  csr[pos] = (unsigned short)s;
}

// ---------------- weight packing into MFMA fragment order ----------------

__global__ void wpack_k(const float* __restrict__ W1, const float* __restrict__ W2,
                        const float* __restrict__ W3, __half* __restrict__ B1,
                        __half* __restrict__ B2, __half* __restrict__ B3) {
  int which = blockIdx.x >> 7;
  int c = blockIdx.x & 127;
  const float* W = which == 0 ? W1 : (which == 1 ? W2 : W3);
  __half* Bp = which == 0 ? B1 : (which == 1 ? B2 : B3);
  int kq = c >> 4, wcf = c & 15;
  int t = threadIdx.x;
  int l = t >> 2;
  int j0 = (t & 3) * 2;
  int li = l & 15, lg = l >> 4;
  int n = wcf * 16 + li;
  int k = kq * 32 + lg * 8 + j0;
  __half2 v;
  v.x = __float2half_rn(W[(size_t)k * 256 + n]);
  v.y = __float2half_rn(W[(size_t)(k + 1) * 256 + n]);
  *reinterpret_cast<__half2*>(Bp + (size_t)c * 512 + 2 * t) = v;
}

__global__ void lwpack_k(const float* __restrict__ l1w, __half* __restrict__ Pp) {
  int b = blockIdx.x;
  int l = b >> 4, cp = b & 15;
  int kq = cp >> 1, hh = cp & 1;
  int t = threadIdx.x;
  int ln = t >> 2;
  int j0 = (t & 3) * 2;
  int li = ln & 15, lg = ln >> 4;
  int dim = hh * 16 + li;
  int k = kq * 32 + lg * 8 + j0;
  __half2 v;
  v.x = __float2half_rn(l1w[((size_t)l * 256 + k) * 32 + dim]);
  v.y = __float2half_rn(l1w[((size_t)l * 256 + k + 1) * 32 + dim]);
  *reinterpret_cast<__half2*>(Pp + (size_t)b * 512 + 2 * t) = v;
}

// ---------------- shared GEMM body (A in LDS, packed B, low reg pressure) ----------------

__device__ __forceinline__ void gemm_body(
    _Float16 (*As)[LDA], int m0, int tid,
    const __half* __restrict__ Bp, const __half* __restrict__ Pp,
    const float* __restrict__ dinv, __half* __restrict__ Y,
    float* __restrict__ part) {
  const int lane = tid & 63;
  const int wid = tid >> 6;
  const int wr = wid >> 1, wc = wid & 1;
  const int li = lane & 15, lg = lane >> 4;

  f32x4 acc[2][8];
  #pragma unroll
  for (int i = 0; i < 2; ++i)
    #pragma unroll
    for (int j = 0; j < 8; ++j) acc[i][j] = (f32x4){0.f, 0.f, 0.f, 0.f};
  f32x4 p0 = (f32x4){0.f, 0.f, 0.f, 0.f};
  f32x4 p1 = (f32x4){0.f, 0.f, 0.f, 0.f};

  const __half* bwave = Bp + (size_t)wc * 8 * 512 + lane * 8;
  const __half* pbase = Pp + lane * 8;

  #pragma unroll
  for (int kq = 0; kq < 8; ++kq) {
    int k0 = kq * 32;
    f16x8 a0 = *reinterpret_cast<const f16x8*>(&As[wr * 32 + li][k0 + lg * 8]);
    f16x8 a1 = *reinterpret_cast<const f16x8*>(&As[wr * 32 + 16 + li][k0 + lg * 8]);
    f16x8 ap = *reinterpret_cast<const f16x8*>(&As[wid * 16 + li][k0 + lg * 8]);
    {
      f16x8 b0 = *reinterpret_cast<const f16x8*>(bwave + ((size_t)kq * 16 + 0) * 512);
      f16x8 b1 = *reinterpret_cast<const f16x8*>(bwave + ((size_t)kq * 16 + 1) * 512);
      f16x8 b2 = *reinterpret_cast<const f16x8*>(bwave + ((size_t)kq * 16 + 2) * 512);
      f16x8 b3 = *reinterpret_cast<const f16x8*>(bwave + ((size_t)kq * 16 + 3) * 512);
      acc[0][0] = __builtin_amdgcn_mfma_f32_16x16x32_f16(b0, a0, acc[0][0], 0, 0, 0);
      acc[1][0] = __builtin_amdgcn_mfma_f32_16x16x32_f16(b0, a1, acc[1][0], 0, 0, 0);
      acc[0][1] = __builtin_amdgcn_mfma_f32_16x16x32_f16(b1, a0, acc[0][1], 0, 0, 0);
      acc[1][1] = __builtin_amdgcn_mfma_f32_16x16x32_f16(b1, a1, acc[1][1], 0, 0, 0);
      acc[0][2] = __builtin_amdgcn_mfma_f32_16x16x32_f16(b2, a0, acc[0][2], 0, 0, 0);
      acc[1][2] = __builtin_amdgcn_mfma_f32_16x16x32_f16(b2, a1, acc[1][2], 0, 0, 0);
      acc[0][3] = __builtin_amdgcn_mfma_f32_16x16x32_f16(b3, a0, acc[0][3], 0, 0, 0);
      acc[1][3] = __builtin_amdgcn_mfma_f32_16x16x32_f16(b3, a1, acc[1][3], 0, 0, 0);
    }
    {
      f16x8 b4 = *reinterpret_cast<const f16x8*>(bwave + ((size_t)kq * 16 + 4) * 512);
      f16x8 b5 = *reinterpret_cast<const f16x8*>(bwave + ((size_t)kq * 16 + 5) * 512);
      f16x8 b6 = *reinterpret_cast<const f16x8*>(bwave + ((size_t)kq * 16 + 6) * 512);
      f16x8 b7 = *reinterpret_cast<const f16x8*>(bwave + ((size_t)kq * 16 + 7) * 512);
      acc[0][4] = __builtin_amdgcn_mfma_f32_16x16x32_f16(b4, a0, acc[0][4], 0, 0, 0);
      acc[1][4] = __builtin_amdgcn_mfma_f32_16x16x32_f16(b4, a1, acc[1][4], 0, 0, 0);
      acc[0][5] = __builtin_amdgcn_mfma_f32_16x16x32_f16(b5, a0, acc[0][5], 0, 0, 0);
      acc[1][5] = __builtin_amdgcn_mfma_f32_16x16x32_f16(b5, a1, acc[1][5], 0, 0, 0);
      acc[0][6] = __builtin_amdgcn_mfma_f32_16x16x32_f16(b6, a0, acc[0][6], 0, 0, 0);
      acc[1][6] = __builtin_amdgcn_mfma_f32_16x16x32_f16(b6, a1, acc[1][6], 0, 0, 0);
      acc[0][7] = __builtin_amdgcn_mfma_f32_16x16x32_f16(b7, a0, acc[0][7], 0, 0, 0);
      acc[1][7] = __builtin_amdgcn_mfma_f32_16x16x32_f16(b7, a1, acc[1][7], 0, 0, 0);
    }
    {
      f16x8 bp0 = *reinterpret_cast<const f16x8*>(pbase + ((size_t)kq * 2 + 0) * 512);
      f16x8 bp1 = *reinterpret_cast<const f16x8*>(pbase + ((size_t)kq * 2 + 1) * 512);
      p0 = __builtin_amdgcn_mfma_f32_16x16x32_f16(bp0, ap, p0, 0, 0, 0);
      p1 = __builtin_amdgcn_mfma_f32_16x16x32_f16(bp1, ap, p1, 0, 0, 0);
    }
  }

  __syncthreads();   // all waves done reading As; safe to overwrite

  #pragma unroll
  for (int rf = 0; rf < 2; ++rf) {
    int row = wr * 32 + rf * 16 + li;
    int r = m0 + row;
    float dv = (r < NNODES) ? dinv[r] : 0.f;
    #pragma unroll
    for (int cf = 0; cf < 8; ++cf) {
      int col = wc * 128 + cf * 16 + lg * 4;
      H4 o;
      o.h[0].x = __float2half_rn(acc[rf][cf][0] * dv);
      o.h[0].y = __float2half_rn(acc[rf][cf][1] * dv);
      o.h[1].x = __float2half_rn(acc[rf][cf][2] * dv);
      o.h[1].y = __float2half_rn(acc[rf][cf][3] * dv);
      *reinterpret_cast<H4*>(&As[row][col]) = o;
    }
  }

  int pr = m0 + wid * 16 + li;
  if (pr < NNODES) {
    float4 v0, v1;
    v0.x = p0[0]; v0.y = p0[1]; v0.z = p0[2]; v0.w = p0[3];
    v1.x = p1[0]; v1.y = p1[1]; v1.z = p1[2]; v1.w = p1[3];
    *reinterpret_cast<float4*>(part + (size_t)pr * 32 + lg * 4) = v0;
    *reinterpret_cast<float4*>(part + (size_t)pr * 32 + 16 + lg * 4) = v1;
  }

  __syncthreads();

  #pragma unroll
  for (int l = 0; l < 8; ++l) {
    int f = l * 256 + tid;
    int row = f >> 5, c8 = (f & 31) * 8;
    int gr = m0 + row;
    if (gr < NNODES)
      *reinterpret_cast<H8*>(Y + (size_t)gr * 256 + c8) =
          *reinterpret_cast<const H8*>(&As[row][c8]);
  }
}

// ---------------- layer 0: fp32 state -> fp16 LDS, gemm W1, proj p5 ----------------

__launch_bounds__(256, 4)
__global__ void gemm0_k(const float* __restrict__ Xf, const __half* __restrict__ Bp,
                        const float* __restrict__ dinv, __half* __restrict__ Y,
                        const __half* __restrict__ Pp, float* __restrict__ part) {
  __shared__ _Float16 As[64][LDA];
  const int tid = threadIdx.x;
  const int m0 = blockIdx.x * 64;
  #pragma unroll
  for (int l = 0; l < 8; ++l) {
    int f = l * 256 + tid;
    int row = f >> 5, c8 = (f & 31) * 8;
    int gr = m0 + row; if (gr >= NNODES) gr = NNODES - 1;
    const float* src = Xf + (size_t)gr * 256 + c8;
    float4 u = *reinterpret_cast<const float4*>(src);
    float4 v = *reinterpret_cast<const float4*>(src + 4);
    H8 o;
    o.h[0].x = __float2half_rn(u.x); o.h[0].y = __float2half_rn(u.y);
    o.h[1].x = __float2half_rn(u.z); o.h[1].y = __float2half_rn(u.w);
    o.h[2].x = __float2half_rn(v.x); o.h[2].y = __float2half_rn(v.y);
    o.h[3].x = __float2half_rn(v.z); o.h[3].y = __float2half_rn(v.w);
    *reinterpret_cast<H8*>(&As[row][c8]) = o;
  }
  __syncthreads();
  gemm_body(As, m0, tid, Bp, Pp, dinv, Y, part);
}

// ---------------- layers 1..4: fp16 activations from global, gemm, proj ----------------

__launch_bounds__(256, 4)
__global__ void gemm_k(const __half* __restrict__ Xh, const __half* __restrict__ Bp,
                       const float* __restrict__ dinv, __half* __restrict__ Y,
                       const __half* __restrict__ Pp, float* __restrict__ part) {
  __shared__ _Float16 As[64][LDA];
  const int tid = threadIdx.x;
  const int m0 = blockIdx.x * 64;
  #pragma unroll
  for (int l = 0; l < 8; ++l) {
    int f = l * 256 + tid;
    int row = f >> 5, c8 = (f & 31) * 8;
    int gr = m0 + row; if (gr >= NNODES) gr = NNODES - 1;
    *reinterpret_cast<H8*>(&As[row][c8]) =
        *reinterpret_cast<const H8*>(Xh + (size_t)gr * 256 + c8);
  }
  __syncthreads();
  gemm_body(As, m0, tid, Bp, Pp, dinv, Y, part);
}

// ---------------- proj-only (o5 -> p4): MFMA projection, no main GEMM ----------------

__launch_bounds__(256, 4)
__global__ void proj_k(const __half* __restrict__ Xh, const __half* __restrict__ Pp,
                       float* __restrict__ part) {
  __shared__ _Float16 As[64][LDA];
  const int tid = threadIdx.x;
  const int m0 = blockIdx.x * 64;
  #pragma unroll
  for (int l = 0; l < 8; ++l) {
    int f = l * 256 + tid;
    int row = f >> 5, c8 = (f & 31) * 8;
    int gr = m0 + row; if (gr >= NNODES) gr = NNODES - 1;
    *reinterpret_cast<H8*>(&As[row][c8]) =
        *reinterpret_cast<const H8*>(Xh + (size_t)gr * 256 + c8);
  }
  __syncthreads();

  const int lane = tid & 63;
  const int wid = tid >> 6;
  const int li = lane & 15, lg = lane >> 4;
  const __half* pbase = Pp + lane * 8;

  f32x4 p0 = (f32x4){0.f, 0.f, 0.f, 0.f};
  f32x4 p1 = (f32x4){0.f, 0.f, 0.f, 0.f};
  #pragma unroll
  for (int kq = 0; kq < 8; ++kq) {
    int k0 = kq * 32;
    f16x8 ap = *reinterpret_cast<const f16x8*>(&As[wid * 16 + li][k0 + lg * 8]);
    f16x8 bp0 = *reinterpret_cast<const f16x8*>(pbase + ((size_t)kq * 2 + 0) * 512);
    f16x8 bp1 = *reinterpret_cast<const f16x8*>(pbase + ((size_t)kq * 2 + 1) * 512);
    p0 = __builtin_amdgcn_mfma_f32_16x16x32_f16(bp0, ap, p0, 0, 0, 0);
    p1 = __builtin_amdgcn_mfma_f32_16x16x32_f16(bp1, ap, p1, 0, 0, 0);
  }
  int pr = m0 + wid * 16 + li;
  if (pr < NNODES) {
    float4 v0, v1;
    v0.x = p0[0]; v0.y = p0[1]; v0.z = p0[2]; v0.w = p0[3];
    v1.x = p1[0]; v1.y = p1[1]; v1.z = p1[2]; v1.w = p1[3];
    *reinterpret_cast<float4*>(part + (size_t)pr * 32 + lg * 4) = v0;
    *reinterpret_cast<float4*>(part + (size_t)pr * 32 + 16 + lg * 4) = v1;
  }
}

// ---------------- gather (r5 proven shape): half-wave per node ----------------

__device__ inline void addH8(float* acc, const H8& v) {
  #pragma unroll
  for (int q = 0; q < 4; ++q) {
    acc[q * 2 + 0] += __low2float(v.h[q]);
    acc[q * 2 + 1] += __high2float(v.h[q]);
  }
}

__global__ void gather_k(const __half* __restrict__ ysh, const int* __restrict__ rs,
                         const unsigned short* __restrict__ csr, const float* __restrict__ dinv,
                         const float* __restrict__ bias, __half* __restrict__ out) {
  int tid = threadIdx.x;
  int lane = tid & 63;
  int wave = (blockIdx.x * blockDim.x + tid) >> 6;
  int d = wave * 2 + (lane >> 5);
  int c8 = (lane & 31) * 8;

  float acc[8];
  H8 self = *reinterpret_cast<const H8*>(ysh + (size_t)d * 256 + c8);
  #pragma unroll
  for (int q = 0; q < 4; ++q) {
    acc[q * 2 + 0] = __low2float(self.h[q]);
    acc[q * 2 + 1] = __high2float(self.h[q]);
  }

  int e = rs[d], end = rs[d + 1];
  for (; e + 3 < end; e += 4) {
    int s0 = csr[e], s1 = csr[e + 1], s2 = csr[e + 2], s3 = csr[e + 3];
    H8 v0 = *reinterpret_cast<const H8*>(ysh + (size_t)s0 * 256 + c8);
    H8 v1 = *reinterpret_cast<const H8*>(ysh + (size_t)s1 * 256 + c8);
    H8 v2 = *reinterpret_cast<const H8*>(ysh + (size_t)s2 * 256 + c8);
    H8 v3 = *reinterpret_cast<const H8*>(ysh + (size_t)s3 * 256 + c8);
    addH8(acc, v0);
    addH8(acc, v1);
    addH8(acc, v2);
    addH8(acc, v3);
  }
  for (; e < end; ++e) {
    int s0 = csr[e];
    H8 v0 = *reinterpret_cast<const H8*>(ysh + (size_t)s0 * 256 + c8);
    addH8(acc, v0);
  }

  float dv = dinv[d];
  float4 b0 = *reinterpret_cast<const float4*>(bias + c8);
  float4 b1 = *reinterpret_cast<const float4*>(bias + c8 + 4);
  float r0 = fmaxf(acc[0] * dv + b0.x, 0.f);
  float r1 = fmaxf(acc[1] * dv + b0.y, 0.f);
  float r2 = fmaxf(acc[2] * dv + b0.z, 0.f);
  float r3 = fmaxf(acc[3] * dv + b0.w, 0.f);
  float r4 = fmaxf(acc[4] * dv + b1.x, 0.f);
  float r5 = fmaxf(acc[5] * dv + b1.y, 0.f);
  float r6 = fmaxf(acc[6] * dv + b1.z, 0.f);
  float r7 = fmaxf(acc[7] * dv + b1.w, 0.f);
  H8 o;
  o.h[0].x = __float2half_rn(r0); o.h[0].y = __float2half_rn(r1);
  o.h[1].x = __float2half_rn(r2); o.h[1].y = __float2half_rn(r3);
  o.h[2].x = __float2half_rn(r4); o.h[2].y = __float2half_rn(r5);
  o.h[3].x = __float2half_rn(r6); o.h[3].y = __float2half_rn(r7);
  *reinterpret_cast<H8*>(out + (size_t)d * 256 + c8) = o;
}

// ---------------- fused MLP + readout ----------------

__launch_bounds__(192)
__global__ void mlpfinal_k(const float* __restrict__ p0, const float* __restrict__ p1,
                           const float* __restrict__ p2, const float* __restrict__ p3,
                           const float* __restrict__ p4, const float* __restrict__ p5,
                           const float* __restrict__ action, const float* __restrict__ l1wlast,
                           const float* __restrict__ l1b, const float* __restrict__ l2w,
                           const float* __restrict__ l2b, const float* __restrict__ l3w,
                           const float* __restrict__ l3b, float* __restrict__ out) {
  __shared__ float w2s[1024];
  __shared__ float h1s[6][33];
  __shared__ float red[3];
  int tid = threadIdx.x;
  for (int i = tid; i < 1024; i += 192) w2s[i] = l2w[i];
  int a = tid >> 5, dim = tid & 31;
  int n = blockIdx.x * 6 + a;
  int idx = n * 32 + dim;
  float h1 = l1b[dim] + action[n] * l1wlast[dim]
           + p0[idx] + p1[idx] + p2[idx] + p3[idx] + p4[idx] + p5[idx];
  h1s[a][dim] = fmaxf(h1, 0.f);
  __syncthreads();
  float acc = l2b[dim];
  #pragma unroll
  for (int k = 0; k < 32; ++k) acc += h1s[a][k] * w2s[k * 32 + dim];
  float v = fmaxf(acc, 0.f) * l3w[dim];
  #pragma unroll
  for (int off = 32; off; off >>= 1) v += __shfl_down(v, off, 64);
  int lane = tid & 63, wave = tid >> 6;
  if (lane == 0) red[wave] = v;
  __syncthreads();
  if (tid == 0) out[blockIdx.x] = red[0] + red[1] + red[2] + l3b[0];
}

// ---------------- host ----------------

extern "C" void kernel_launch(void* const* d_in, const int* in_sizes, int n_in,
                              void* d_out, int out_size, void* d_ws, size_t ws_size,
                              hipStream_t stream) {
  const float* state  = (const float*)d_in[0];
  const int*   ei     = (const int*)d_in[1];
  const float* action = (const float*)d_in[2];
  const float* W1 = (const float*)d_in[3];
  const float* b1 = (const float*)d_in[4];
  const float* W2 = (const float*)d_in[5];
  const float* b2 = (const float*)d_in[6];
  const float* W3 = (const float*)d_in[7];
  const float* b3 = (const float*)d_in[8];
  const float* l1w = (const float*)d_in[13];
  const float* l1b = (const float*)d_in[14];
  const float* l2w = (const float*)d_in[15];
  const float* l2b = (const float*)d_in[16];
  const float* l3w = (const float*)d_in[17];
  const float* l3b = (const float*)d_in[18];
  float* out = (float*)d_out;

  char* base = (char*)d_ws;
  size_t off = 0;
  auto carve = [&](size_t bytes) {
    char* q = base + off;
    off += (bytes + 255) & ~(size_t)255;
    return q;
  };
  __half* ysh   = (__half*)carve((size_t)NNODES * 256 * 2);
  __half* obufh = (__half*)carve((size_t)NNODES * 256 * 2);
  __half* Bp1   = (__half*)carve(128 * 512 * 2);
  __half* Bp2   = (__half*)carve(128 * 512 * 2);
  __half* Bp3   = (__half*)carve(128 * 512 * 2);
  __half* Pp    = (__half*)carve(96 * 512 * 2);   // 6 slices x 16 chunks
  float* parts[6];
  for (int i = 0; i < 6; ++i) parts[i] = (float*)carve((size_t)NNODES * 32 * 4);
  float* dinv  = (float*)carve(NNODES * 4);
  char*  zbase = (char*)carve(0);
  int*   deg   = (int*)carve(NNODES * 4);
  int*   cursor= (int*)carve(NNODES * 4);
  size_t zlen  = (size_t)((char*)carve(0) - zbase);
  int*   rs    = (int*)carve((NNODES + 1) * 4);
  unsigned short* csr = (unsigned short*)carve((size_t)NEDGES * 2);
  int*   bsum  = (int*)carve(256 * 4);

  hipMemsetAsync(zbase, 0, zlen, stream);

  wpack_k<<<128 * 3, 256, 0, stream>>>(W1, W2, W3, Bp1, Bp2, Bp3);
  lwpack_k<<<96, 256, 0, stream>>>(l1w, Pp);

  count_deg_k<<<NEDGES / 256, 256, 0, stream>>>(ei, deg);
  int nb = (NNODES + 255) / 256;
  scan1_k<<<nb, 256, 0, stream>>>(deg, rs, bsum, dinv);
  scan2_k<<<1, 256, 0, stream>>>(bsum, nb);
  scan3_k<<<nb, 256, 0, stream>>>(rs, bsum);
  scatter_k<<<NEDGES / 256, 256, 0, stream>>>(ei, rs, cursor, csr);

  int mblocks = (NNODES + 63) / 64;   // 938
  const __half* Bps[5] = {Bp1, Bp2, Bp3, Bp3, Bp3};
  const float*  bs[5]  = {b1, b2, b3, b3, b3};

  // layer 0: state @ W1 -> ysh ; proj p5 (state @ lw5)
  gemm0_k<<<mblocks, 256, 0, stream>>>(state, Bp1, dinv, ysh,
                                       Pp + (size_t)5 * 16 * 512, parts[5]);
  for (int layer = 1; layer < 5; ++layer) {
    gather_k<<<NNODES / 8, 256, 0, stream>>>(ysh, rs, csr, dinv, bs[layer - 1], obufh);
    gemm_k<<<mblocks, 256, 0, stream>>>(obufh, Bps[layer], dinv, ysh,
                                        Pp + (size_t)(layer - 1) * 16 * 512, parts[layer - 1]);
  }
  // layer 5: gather -> o5 ; proj -> p4
  gather_k<<<NNODES / 8, 256, 0, stream>>>(ysh, rs, csr, dinv, b3, obufh);
  proj_k<<<mblocks, 256, 0, stream>>>(obufh, Pp + (size_t)4 * 16 * 512, parts[4]);

  mlpfinal_k<<<NGRAPH, 192, 0, stream>>>(parts[0], parts[1], parts[2], parts[3], parts[4],
                                         parts[5], action, l1w + 1536 * 32, l1b, l2w, l2b,
                                         l3w, l3b, out);
}

// Round 12
// 642.166 us; speedup vs baseline: 1.3184x; 1.0070x over previous
//
#include <hip/hip_runtime.h>
#include <hip/hip_fp16.h>

#define NNODES 60000
#define NEDGES 960000
#define NGRAPH 10000

struct __align__(16) H8 { __half2 h[4]; };
struct __align__(8)  H4 { __half2 h[2]; };

typedef _Float16 f16x8 __attribute__((ext_vector_type(8)));
typedef float f32x4 __attribute__((ext_vector_type(4)));

#define LDA 264   // halves; 528 B row stride (16B-aligned rows)

// ---------------- degree / CSR build ----------------

__global__ void count_deg_k(const int* __restrict__ ei, int* __restrict__ deg) {
  int e = blockIdx.x * blockDim.x + threadIdx.x;
  atomicAdd(&deg[ei[NEDGES + e]], 1);
}

__global__ void scan1_k(const int* __restrict__ deg, int* __restrict__ rs,
                        int* __restrict__ bsum, float* __restrict__ dinv) {
  __shared__ int s[256];
  int tid = threadIdx.x;
  int i = blockIdx.x * 256 + tid;
  int v = (i < NNODES) ? deg[i] : 0;
  if (i < NNODES) dinv[i] = rsqrtf((float)v + 1.0f);
  int x = v;
  s[tid] = x; __syncthreads();
  #pragma unroll
  for (int off = 1; off < 256; off <<= 1) {
    int t = (tid >= off) ? s[tid - off] : 0;
    __syncthreads();
    x += t; s[tid] = x; __syncthreads();
  }
  if (i < NNODES) rs[i] = x - v;
  if (tid == 255) bsum[blockIdx.x] = x;
}

__global__ void scan2_k(int* __restrict__ bsum, int nb) {
  __shared__ int s[256];
  int tid = threadIdx.x;
  int v = (tid < nb) ? bsum[tid] : 0;
  int x = v; s[tid] = x; __syncthreads();
  #pragma unroll
  for (int off = 1; off < 256; off <<= 1) {
    int t = (tid >= off) ? s[tid - off] : 0;
    __syncthreads();
    x += t; s[tid] = x; __syncthreads();
  }
  if (tid < nb) bsum[tid] = x - v;
}

__global__ void scan3_k(int* __restrict__ rs, const int* __restrict__ bsum) {
  int i = blockIdx.x * 256 + threadIdx.x;
  if (i < NNODES) rs[i] += bsum[blockIdx.x];
  if (i == 0) rs[NNODES] = NEDGES;
}

__global__ void scatter_k(const int* __restrict__ ei, const int* __restrict__ rs,
                          int* __restrict__ cursor, unsigned short* __restrict__ csr) {
  int e = blockIdx.x * blockDim.x + threadIdx.x;
  int s = ei[e], d = ei[NEDGES + e];
  int pos = rs[d] + atomicAdd(&cursor[d], 1);
  csr[pos] = (unsigned short)s;
}

// ---------------- weight packing into MFMA fragment order ----------------
// Bp chunk c = kq*16 + cfi (cfi = col-frag 0..15, cols cfi*16..+16). 1KB/chunk.

__global__ void wpack_k(const float* __restrict__ W1, const float* __restrict__ W2,
                        const float* __restrict__ W3, __half* __restrict__ B1,
                        __half* __restrict__ B2, __half* __restrict__ B3) {
  int which = blockIdx.x >> 7;
  int c = blockIdx.x & 127;
  const float* W = which == 0 ? W1 : (which == 1 ? W2 : W3);
  __half* Bp = which == 0 ? B1 : (which == 1 ? B2 : B3);
  int kq = c >> 4, wcf = c & 15;
  int t = threadIdx.x;
  int l = t >> 2;
  int j0 = (t & 3) * 2;
  int li = l & 15, lg = l >> 4;
  int n = wcf * 16 + li;
  int k = kq * 32 + lg * 8 + j0;
  __half2 v;
  v.x = __float2half_rn(W[(size_t)k * 256 + n]);
  v.y = __float2half_rn(W[(size_t)(k + 1) * 256 + n]);
  *reinterpret_cast<__half2*>(Bp + (size_t)c * 512 + 2 * t) = v;
}

__global__ void lwpack_k(const float* __restrict__ l1w, __half* __restrict__ Pp) {
  int b = blockIdx.x;
  int l = b >> 4, cp = b & 15;
  int kq = cp >> 1, hh = cp & 1;
  int t = threadIdx.x;
  int ln = t >> 2;
  int j0 = (t & 3) * 2;
  int li = ln & 15, lg = ln >> 4;
  int dim = hh * 16 + li;
  int k = kq * 32 + lg * 8 + j0;
  __half2 v;
  v.x = __float2half_rn(l1w[((size_t)l * 256 + k) * 32 + dim]);
  v.y = __float2half_rn(l1w[((size_t)l * 256 + k + 1) * 32 + dim]);
  *reinterpret_cast<__half2*>(Pp + (size_t)b * 512 + 2 * t) = v;
}

// ---------------- GEMM body: BM=32, BN=128, 4 waves (2 row-frags x 2 col-halves) ----------
// block bid: m0=(bid>>1)*32, nh=bid&1 (col half 0..127 / 128..255 of output).
// wave wid: rows (wid>>1)*16..+16, cols (wid&1)*64..+64 (4 frags). acc = 4 f32x4.
// proj (nh==0 blocks): p += mfma(Pp frag[wid&1], a) -> part[rows][dims (wid&1)*16..+16].

__device__ __forceinline__ void gemm_body32(
    _Float16 (*As)[LDA], int m0, int nh, int tid,
    const __half* __restrict__ Bp, const __half* __restrict__ Pp,
    const float* __restrict__ dinv, __half* __restrict__ Y,
    float* __restrict__ part) {
  const int lane = tid & 63;
  const int wid = tid >> 6;
  const int wr2 = wid >> 1, wcl = wid & 1;
  const int li = lane & 15, lg = lane >> 4;

  f32x4 acc[4];
  #pragma unroll
  for (int j = 0; j < 4; ++j) acc[j] = (f32x4){0.f, 0.f, 0.f, 0.f};
  f32x4 p = (f32x4){0.f, 0.f, 0.f, 0.f};

  const __half* bwave = Bp + (size_t)(nh * 8 + wcl * 4) * 512 + lane * 8;
  const __half* pbase = Pp + (size_t)wcl * 512 + lane * 8;

  #pragma unroll
  for (int kq = 0; kq < 8; ++kq) {
    int k0 = kq * 32;
    f16x8 a = *reinterpret_cast<const f16x8*>(&As[wr2 * 16 + li][k0 + lg * 8]);
    f16x8 b0 = *reinterpret_cast<const f16x8*>(bwave + ((size_t)kq * 16 + 0) * 512);
    f16x8 b1 = *reinterpret_cast<const f16x8*>(bwave + ((size_t)kq * 16 + 1) * 512);
    f16x8 b2 = *reinterpret_cast<const f16x8*>(bwave + ((size_t)kq * 16 + 2) * 512);
    f16x8 b3 = *reinterpret_cast<const f16x8*>(bwave + ((size_t)kq * 16 + 3) * 512);
    acc[0] = __builtin_amdgcn_mfma_f32_16x16x32_f16(b0, a, acc[0], 0, 0, 0);
    acc[1] = __builtin_amdgcn_mfma_f32_16x16x32_f16(b1, a, acc[1], 0, 0, 0);
    acc[2] = __builtin_amdgcn_mfma_f32_16x16x32_f16(b2, a, acc[2], 0, 0, 0);
    acc[3] = __builtin_amdgcn_mfma_f32_16x16x32_f16(b3, a, acc[3], 0, 0, 0);
    if (nh == 0) {
      f16x8 bp = *reinterpret_cast<const f16x8*>(pbase + (size_t)kq * 2 * 512);
      p = __builtin_amdgcn_mfma_f32_16x16x32_f16(bp, a, p, 0, 0, 0);
    }
  }

  __syncthreads();   // all waves done reading As; safe to overwrite

  {
    int row = wr2 * 16 + li;
    int r = m0 + row;
    float dv = dinv[r];
    #pragma unroll
    for (int cf = 0; cf < 4; ++cf) {
      int col = wcl * 64 + cf * 16 + lg * 4;
      H4 o;
      o.h[0].x = __float2half_rn(acc[cf][0] * dv);
      o.h[0].y = __float2half_rn(acc[cf][1] * dv);
      o.h[1].x = __float2half_rn(acc[cf][2] * dv);
      o.h[1].y = __float2half_rn(acc[cf][3] * dv);
      *reinterpret_cast<H4*>(&As[row][col]) = o;
    }
    if (nh == 0) {
      float4 v;
      v.x = p[0]; v.y = p[1]; v.z = p[2]; v.w = p[3];
      *reinterpret_cast<float4*>(part + (size_t)r * 32 + wcl * 16 + lg * 4) = v;
    }
  }

  __syncthreads();

  // store 32 rows x 128 halves: 512 H8, 2 per thread
  #pragma unroll
  for (int l = 0; l < 2; ++l) {
    int f = l * 256 + tid;
    int row = f >> 4, c8 = (f & 15) * 8;
    *reinterpret_cast<H8*>(Y + (size_t)(m0 + row) * 256 + nh * 128 + c8) =
        *reinterpret_cast<const H8*>(&As[row][c8]);
  }
}

// ---------------- layer 0: fp32 state -> fp16 LDS, gemm W1, proj p5 ----------------

__launch_bounds__(256, 6)
__global__ void gemm0_k(const float* __restrict__ Xf, const __half* __restrict__ Bp,
                        const float* __restrict__ dinv, __half* __restrict__ Y,
                        const __half* __restrict__ Pp, float* __restrict__ part) {
  __shared__ _Float16 As[32][LDA];
  const int tid = threadIdx.x;
  const int m0 = (blockIdx.x >> 1) * 32;
  const int nh = blockIdx.x & 1;
  #pragma unroll
  for (int l = 0; l < 4; ++l) {
    int f = l * 256 + tid;
    int row = f >> 5, c8 = (f & 31) * 8;
    const float* src = Xf + (size_t)(m0 + row) * 256 + c8;
    float4 u = *reinterpret_cast<const float4*>(src);
    float4 v = *reinterpret_cast<const float4*>(src + 4);
    H8 o;
    o.h[0].x = __float2half_rn(u.x); o.h[0].y = __float2half_rn(u.y);
    o.h[1].x = __float2half_rn(u.z); o.h[1].y = __float2half_rn(u.w);
    o.h[2].x = __float2half_rn(v.x); o.h[2].y = __float2half_rn(v.y);
    o.h[3].x = __float2half_rn(v.z); o.h[3].y = __float2half_rn(v.w);
    *reinterpret_cast<H8*>(&As[row][c8]) = o;
  }
  __syncthreads();
  gemm_body32(As, m0, nh, tid, Bp, Pp, dinv, Y, part);
}

// ---------------- layers 1..4: fp16 activations from global, gemm, proj ----------------

__launch_bounds__(256, 6)
__global__ void gemm_k(const __half* __restrict__ Xh, const __half* __restrict__ Bp,
                       const float* __restrict__ dinv, __half* __restrict__ Y,
                       const __half* __restrict__ Pp, float* __restrict__ part) {
  __shared__ _Float16 As[32][LDA];
  const int tid = threadIdx.x;
  const int m0 = (blockIdx.x >> 1) * 32;
  const int nh = blockIdx.x & 1;
  #pragma unroll
  for (int l = 0; l < 4; ++l) {
    int f = l * 256 + tid;
    int row = f >> 5, c8 = (f & 31) * 8;
    *reinterpret_cast<H8*>(&As[row][c8]) =
        *reinterpret_cast<const H8*>(Xh + (size_t)(m0 + row) * 256 + c8);
  }
  __syncthreads();
  gemm_body32(As, m0, nh, tid, Bp, Pp, dinv, Y, part);
}

// ---------------- proj-only (o5 -> p4): MFMA projection, no main GEMM ----------------

__launch_bounds__(256, 4)
__global__ void proj_k(const __half* __restrict__ Xh, const __half* __restrict__ Pp,
                       float* __restrict__ part) {
  __shared__ _Float16 As[64][LDA];
  const int tid = threadIdx.x;
  const int m0 = blockIdx.x * 64;
  #pragma unroll
  for (int l = 0; l < 8; ++l) {
    int f = l * 256 + tid;
    int row = f >> 5, c8 = (f & 31) * 8;
    *reinterpret_cast<H8*>(&As[row][c8]) =
        *reinterpret_cast<const H8*>(Xh + (size_t)(m0 + row) * 256 + c8);
  }
  __syncthreads();

  const int lane = tid & 63;
  const int wid = tid >> 6;
  const int li = lane & 15, lg = lane >> 4;
  const __half* pbase = Pp + lane * 8;

  f32x4 p0 = (f32x4){0.f, 0.f, 0.f, 0.f};
  f32x4 p1 = (f32x4){0.f, 0.f, 0.f, 0.f};
  #pragma unroll
  for (int kq = 0; kq < 8; ++kq) {
    int k0 = kq * 32;
    f16x8 ap = *reinterpret_cast<const f16x8*>(&As[wid * 16 + li][k0 + lg * 8]);
    f16x8 bp0 = *reinterpret_cast<const f16x8*>(pbase + ((size_t)kq * 2 + 0) * 512);
    f16x8 bp1 = *reinterpret_cast<const f16x8*>(pbase + ((size_t)kq * 2 + 1) * 512);
    p0 = __builtin_amdgcn_mfma_f32_16x16x32_f16(bp0, ap, p0, 0, 0, 0);
    p1 = __builtin_amdgcn_mfma_f32_16x16x32_f16(bp1, ap, p1, 0, 0, 0);
  }
  int pr = m0 + wid * 16 + li;
  {
    float4 v0, v1;
    v0.x = p0[0]; v0.y = p0[1]; v0.z = p0[2]; v0.w = p0[3];
    v1.x = p1[0]; v1.y = p1[1]; v1.z = p1[2]; v1.w = p1[3];
    *reinterpret_cast<float4*>(part + (size_t)pr * 32 + lg * 4) = v0;
    *reinterpret_cast<float4*>(part + (size_t)pr * 32 + 16 + lg * 4) = v1;
  }
}

// ---------------- gather (r5 proven shape): half-wave per node ----------------

__device__ inline void addH8(float* acc, const H8& v) {
  #pragma unroll
  for (int q = 0; q < 4; ++q) {
    acc[q * 2 + 0] += __low2float(v.h[q]);
    acc[q * 2 + 1] += __high2float(v.h[q]);
  }
}

__global__ void gather_k(const __half* __restrict__ ysh, const int* __restrict__ rs,
                         const unsigned short* __restrict__ csr, const float* __restrict__ dinv,
                         const float* __restrict__ bias, __half* __restrict__ out) {
  int tid = threadIdx.x;
  int lane = tid & 63;
  int wave = (blockIdx.x * blockDim.x + tid) >> 6;
  int d = wave * 2 + (lane >> 5);
  int c8 = (lane & 31) * 8;

  float acc[8];
  H8 self = *reinterpret_cast<const H8*>(ysh + (size_t)d * 256 + c8);
  #pragma unroll
  for (int q = 0; q < 4; ++q) {
    acc[q * 2 + 0] = __low2float(self.h[q]);
    acc[q * 2 + 1] = __high2float(self.h[q]);
  }

  int e = rs[d], end = rs[d + 1];
  for (; e + 3 < end; e += 4) {
    int s0 = csr[e], s1 = csr[e + 1], s2 = csr[e + 2], s3 = csr[e + 3];
    H8 v0 = *reinterpret_cast<const H8*>(ysh + (size_t)s0 * 256 + c8);
    H8 v1 = *reinterpret_cast<const H8*>(ysh + (size_t)s1 * 256 + c8);
    H8 v2 = *reinterpret_cast<const H8*>(ysh + (size_t)s2 * 256 + c8);
    H8 v3 = *reinterpret_cast<const H8*>(ysh + (size_t)s3 * 256 + c8);
    addH8(acc, v0);
    addH8(acc, v1);
    addH8(acc, v2);
    addH8(acc, v3);
  }
  for (; e < end; ++e) {
    int s0 = csr[e];
    H8 v0 = *reinterpret_cast<const H8*>(ysh + (size_t)s0 * 256 + c8);
    addH8(acc, v0);
  }

  float dv = dinv[d];
  float4 b0 = *reinterpret_cast<const float4*>(bias + c8);
  float4 b1 = *reinterpret_cast<const float4*>(bias + c8 + 4);
  float r0 = fmaxf(acc[0] * dv + b0.x, 0.f);
  float r1 = fmaxf(acc[1] * dv + b0.y, 0.f);
  float r2 = fmaxf(acc[2] * dv + b0.z, 0.f);
  float r3 = fmaxf(acc[3] * dv + b0.w, 0.f);
  float r4 = fmaxf(acc[4] * dv + b1.x, 0.f);
  float r5 = fmaxf(acc[5] * dv + b1.y, 0.f);
  float r6 = fmaxf(acc[6] * dv + b1.z, 0.f);
  float r7 = fmaxf(acc[7] * dv + b1.w, 0.f);
  H8 o;
  o.h[0].x = __float2half_rn(r0); o.h[0].y = __float2half_rn(r1);
  o.h[1].x = __float2half_rn(r2); o.h[1].y = __float2half_rn(r3);
  o.h[2].x = __float2half_rn(r4); o.h[2].y = __float2half_rn(r5);
  o.h[3].x = __float2half_rn(r6); o.h[3].y = __float2half_rn(r7);
  *reinterpret_cast<H8*>(out + (size_t)d * 256 + c8) = o;
}

// ---------------- fused MLP + readout ----------------

__launch_bounds__(192)
__global__ void mlpfinal_k(const float* __restrict__ p0, const float* __restrict__ p1,
                           const float* __restrict__ p2, const float* __restrict__ p3,
                           const float* __restrict__ p4, const float* __restrict__ p5,
                           const float* __restrict__ action, const float* __restrict__ l1wlast,
                           const float* __restrict__ l1b, const float* __restrict__ l2w,
                           const float* __restrict__ l2b, const float* __restrict__ l3w,
                           const float* __restrict__ l3b, float* __restrict__ out) {
  __shared__ float w2s[1024];
  __shared__ float h1s[6][33];
  __shared__ float red[3];
  int tid = threadIdx.x;
  for (int i = tid; i < 1024; i += 192) w2s[i] = l2w[i];
  int a = tid >> 5, dim = tid & 31;
  int n = blockIdx.x * 6 + a;
  int idx = n * 32 + dim;
  float h1 = l1b[dim] + action[n] * l1wlast[dim]
           + p0[idx] + p1[idx] + p2[idx] + p3[idx] + p4[idx] + p5[idx];
  h1s[a][dim] = fmaxf(h1, 0.f);
  __syncthreads();
  float acc = l2b[dim];
  #pragma unroll
  for (int k = 0; k < 32; ++k) acc += h1s[a][k] * w2s[k * 32 + dim];
  float v = fmaxf(acc, 0.f) * l3w[dim];
  #pragma unroll
  for (int off = 32; off; off >>= 1) v += __shfl_down(v, off, 64);
  int lane = tid & 63, wave = tid >> 6;
  if (lane == 0) red[wave] = v;
  __syncthreads();
  if (tid == 0) out[blockIdx.x] = red[0] + red[1] + red[2] + l3b[0];
}

// ---------------- host ----------------

extern "C" void kernel_launch(void* const* d_in, const int* in_sizes, int n_in,
                              void* d_out, int out_size, void* d_ws, size_t ws_size,
                              hipStream_t stream) {
  const float* state  = (const float*)d_in[0];
  const int*   ei     = (const int*)d_in[1];
  const float* action = (const float*)d_in[2];
  const float* W1 = (const float*)d_in[3];
  const float* b1 = (const float*)d_in[4];
  const float* W2 = (const float*)d_in[5];
  const float* b2 = (const float*)d_in[6];
  const float* W3 = (const float*)d_in[7];
  const float* b3 = (const float*)d_in[8];
  const float* l1w = (const float*)d_in[13];
  const float* l1b = (const float*)d_in[14];
  const float* l2w = (const float*)d_in[15];
  const float* l2b = (const float*)d_in[16];
  const float* l3w = (const float*)d_in[17];
  const float* l3b = (const float*)d_in[18];
  float* out = (float*)d_out;

  char* base = (char*)d_ws;
  size_t off = 0;
  auto carve = [&](size_t bytes) {
    char* q = base + off;
    off += (bytes + 255) & ~(size_t)255;
    return q;
  };
  __half* ysh   = (__half*)carve((size_t)NNODES * 256 * 2);
  __half* obufh = (__half*)carve((size_t)NNODES * 256 * 2);
  __half* Bp1   = (__half*)carve(128 * 512 * 2);
  __half* Bp2   = (__half*)carve(128 * 512 * 2);
  __half* Bp3   = (__half*)carve(128 * 512 * 2);
  __half* Pp    = (__half*)carve(96 * 512 * 2);   // 6 slices x 16 chunks
  float* parts[6];
  for (int i = 0; i < 6; ++i) parts[i] = (float*)carve((size_t)NNODES * 32 * 4);
  float* dinv  = (float*)carve(NNODES * 4);
  char*  zbase = (char*)carve(0);
  int*   deg   = (int*)carve(NNODES * 4);
  int*   cursor= (int*)carve(NNODES * 4);
  size_t zlen  = (size_t)((char*)carve(0) - zbase);
  int*   rs    = (int*)carve((NNODES + 1) * 4);
  unsigned short* csr = (unsigned short*)carve((size_t)NEDGES * 2);
  int*   bsum  = (int*)carve(256 * 4);

  hipMemsetAsync(zbase, 0, zlen, stream);

  wpack_k<<<128 * 3, 256, 0, stream>>>(W1, W2, W3, Bp1, Bp2, Bp3);
  lwpack_k<<<96, 256, 0, stream>>>(l1w, Pp);

  count_deg_k<<<NEDGES / 256, 256, 0, stream>>>(ei, deg);
  int nb = (NNODES + 255) / 256;
  scan1_k<<<nb, 256, 0, stream>>>(deg, rs, bsum, dinv);
  scan2_k<<<1, 256, 0, stream>>>(bsum, nb);
  scan3_k<<<nb, 256, 0, stream>>>(rs, bsum);
  scatter_k<<<NEDGES / 256, 256, 0, stream>>>(ei, rs, cursor, csr);

  int gblocks = (NNODES / 32) * 2;   // 3750
  const __half* Bps[5] = {Bp1, Bp2, Bp3, Bp3, Bp3};
  const float*  bs[5]  = {b1, b2, b3, b3, b3};

  // layer 0: state @ W1 -> ysh ; proj p5 (state @ lw5)
  gemm0_k<<<gblocks, 256, 0, stream>>>(state, Bp1, dinv, ysh,
                                       Pp + (size_t)5 * 16 * 512, parts[5]);
  for (int layer = 1; layer < 5; ++layer) {
    gather_k<<<NNODES / 8, 256, 0, stream>>>(ysh, rs, csr, dinv, bs[layer - 1], obufh);
    gemm_k<<<gblocks, 256, 0, stream>>>(obufh, Bps[layer], dinv, ysh,
                                        Pp + (size_t)(layer - 1) * 16 * 512, parts[layer - 1]);
  }
  // layer 5: gather -> o5 ; proj -> p4
  gather_k<<<NNODES / 8, 256, 0, stream>>>(ysh, rs, csr, dinv, b3, obufh);
  proj_k<<<NNODES / 64, 256, 0, stream>>>(obufh, Pp + (size_t)4 * 16 * 512, parts[4]);

  mlpfinal_k<<<NGRAPH, 192, 0, stream>>>(parts[0], parts[1], parts[2], parts[3], parts[4],
                                         parts[5], action, l1w + 1536 * 32, l1b, l2w, l2b,
                                         l3w, l3b, out);
}